// Round 13
// baseline (869.620 us; speedup 1.0000x reference)
//
#include <hip/hip_runtime.h>
#include <hip/hip_bf16.h>
#include <hip/hip_cooperative_groups.h>

namespace cg = cooperative_groups;

#define BN_EPS 1e-5f

typedef short bf16x8 __attribute__((ext_vector_type(8)));
typedef float f32x4 __attribute__((ext_vector_type(4)));

static __device__ __forceinline__ unsigned short f2bf(float f) {
    unsigned u = __float_as_uint(f);
    unsigned r = (u + 0x7FFF + ((u >> 16) & 1)) >> 16;
    return (unsigned short)r;
}
static __device__ __forceinline__ float bf2f(unsigned short s) {
    return __uint_as_float((unsigned)s << 16);
}
__device__ __forceinline__ int pad8i(int c) { return (c + 7) & ~7; }

#define BIN_SHIFT 9
#define BIN_NODES 512
#define P1_CHUNK 8192
#define IMG_CAP 12288
#define SCAN_CHUNK 1024
#define COOP_GRID 512

// ---------------- cooperative preprocessing mega-kernel ----------------
// stages (grid.sync between): zero -> binhist -> bin scan -> phase1 ->
// bincount+dinv -> padded row scan (3 passes) -> phase2 CSR build.
struct PreArgs {
    const int* src; const int* dst; int e;
    int* bincnt; int* bstart_e; int* bincur; int* ebuf;
    int* cnt; float* dinv; int* bsums; int* row_start; int* csr; int* cursor;
    unsigned short* ha_sent; float* pooled;
    int n; int nbins; int nb; int gpool;
};

__global__ __launch_bounds__(256) void preprocess_coop(PreArgs a) {
    cg::grid_group grid = cg::this_grid();
    __shared__ int smem[IMG_CAP + BIN_NODES];        // 50 KB union
    int t = threadIdx.x, blk = blockIdx.x, nblk = gridDim.x;
    int gtid = blk * 256 + t, gstride = nblk * 256;

    // ---- S0: zero scratch the harness poisoned ----
    for (int i = gtid; i < a.nbins; i += gstride) { a.bincnt[i] = 0; a.bincur[i] = 0; }
    for (int i = gtid; i < a.n; i += gstride) a.cursor[i] = 0;
    for (int i = gtid; i < a.gpool * 64; i += gstride) a.pooled[i] = 0.f;
    if (gtid < 64) a.ha_sent[gtid] = 0;
    grid.sync();

    // ---- S1: bin-level histogram ----
    int nchunks = (a.e + P1_CHUNK - 1) / P1_CHUNK;
    for (int c = blk; c < nchunks; c += nblk) {
        int* hist = smem;
        hist[t] = 0;
        __syncthreads();
        int c0 = c * P1_CHUNK, iend = min(c0 + P1_CHUNK, a.e);
        for (int i = c0 + t; i < iend; i += 256)
            atomicAdd(&hist[a.dst[i] >> BIN_SHIFT], 1);
        __syncthreads();
        if (t < a.nbins && hist[t] > 0) atomicAdd(&a.bincnt[t], hist[t]);
        __syncthreads();
    }
    grid.sync();

    // ---- S2: tiny exclusive scan over bins ----
    if (blk == 0 && t == 0) {
        int acc = 0;
        for (int i = 0; i < a.nbins; i++) { a.bstart_e[i] = acc; acc += a.bincnt[i]; }
        a.bstart_e[a.nbins] = acc;
    }
    grid.sync();

    // ---- S3: phase1 partition edges into bins ----
    for (int c = blk; c < nchunks; c += nblk) {
        int* hist = smem; int* base = smem + 256; int* cur = smem + 512;
        hist[t] = 0;
        __syncthreads();
        int c0 = c * P1_CHUNK, iend = min(c0 + P1_CHUNK, a.e);
        for (int i = c0 + t; i < iend; i += 256)
            atomicAdd(&hist[a.dst[i] >> BIN_SHIFT], 1);
        __syncthreads();
        if (t < a.nbins && hist[t] > 0)
            base[t] = a.bstart_e[t] + atomicAdd(&a.bincur[t], hist[t]);
        cur[t] = 0;
        __syncthreads();
        for (int i = c0 + t; i < iend; i += 256) {
            int s = a.src[i], d = a.dst[i];
            int b = d >> BIN_SHIFT;
            int r = atomicAdd(&cur[b], 1);
            a.ebuf[base[b] + r] = s | ((d & (BIN_NODES - 1)) << 17);
        }
        __syncthreads();
    }
    grid.sync();

    // ---- S4: per-node counts + dinv ----
    for (int b = blk; b < a.nbins; b += nblk) {
        int* c512 = smem;
        for (int k = t; k < BIN_NODES; k += 256) c512[k] = 0;
        __syncthreads();
        int e0 = a.bstart_e[b], e1 = a.bstart_e[b + 1];
        for (int j = e0 + t; j < e1; j += 256)
            atomicAdd(&c512[a.ebuf[j] >> 17], 1);
        __syncthreads();
        int n0 = b * BIN_NODES;
        for (int k = t; k < BIN_NODES; k += 256) {
            int i = n0 + k;
            if (i < a.n) {
                int c = c512[k];
                a.cnt[i] = c;
                a.dinv[i] = rsqrtf((float)(c + 1));
            }
        }
        __syncthreads();
    }
    grid.sync();

    // ---- S5a: padded scan, block sums ----
    for (int b = blk; b < a.nb; b += nblk) {
        int* sd = smem;
        int base0 = b * SCAN_CHUNK;
        int s = 0;
        for (int i = t; i < SCAN_CHUNK; i += 256) {
            int idx = base0 + i;
            if (idx < a.n) s += pad8i(a.cnt[idx]);
        }
        sd[t] = s;
        __syncthreads();
        for (int off = 128; off > 0; off >>= 1) {
            if (t < off) sd[t] += sd[t + off];
            __syncthreads();
        }
        if (t == 0) a.bsums[b] = sd[0];
        __syncthreads();
    }
    grid.sync();
    if (blk == 0 && t == 0) {
        int acc = 0;
        for (int i = 0; i < a.nb; i++) { int v = a.bsums[i]; a.bsums[i] = acc; acc += v; }
    }
    grid.sync();
    // ---- S5c: scan write ----
    for (int b = blk; b < a.nb; b += nblk) {
        int* sd = smem;
        int base0 = b * SCAN_CHUNK + t * 4;
        int v0 = 0, v1 = 0, v2 = 0, v3 = 0;
        if (base0 + 0 < a.n) v0 = pad8i(a.cnt[base0 + 0]);
        if (base0 + 1 < a.n) v1 = pad8i(a.cnt[base0 + 1]);
        if (base0 + 2 < a.n) v2 = pad8i(a.cnt[base0 + 2]);
        if (base0 + 3 < a.n) v3 = pad8i(a.cnt[base0 + 3]);
        int tsum = v0 + v1 + v2 + v3;
        sd[t] = tsum;
        __syncthreads();
        for (int off = 1; off < 256; off <<= 1) {
            int x = (t >= off) ? sd[t - off] : 0;
            __syncthreads();
            sd[t] += x;
            __syncthreads();
        }
        int excl = sd[t] - tsum + a.bsums[b];
        if (base0 + 0 < a.n) a.row_start[base0 + 0] = excl;
        if (base0 + 1 < a.n) a.row_start[base0 + 1] = excl + v0;
        if (base0 + 2 < a.n) a.row_start[base0 + 2] = excl + v0 + v1;
        if (base0 + 3 < a.n) a.row_start[base0 + 3] = excl + v0 + v1 + v2;
        if (a.n - 1 >= base0 && a.n - 1 < base0 + 4)
            a.row_start[a.n] = excl + v0 + v1 + v2 + v3;
        __syncthreads();
    }
    grid.sync();

    // ---- S6: phase2 CSR build ----
    for (int b = blk; b < a.nbins; b += nblk) {
        int* image = smem; int* lcur = smem + IMG_CAP;
        __syncthreads();
        int n0 = b * BIN_NODES;
        int n1 = min(n0 + BIN_NODES, a.n);
        int rbase = a.row_start[n0];
        int rspan = a.row_start[n1] - rbase;
        int e0 = a.bstart_e[b], e1 = a.bstart_e[b + 1];
        for (int k = t; k < BIN_NODES; k += 256) lcur[k] = 0;
        if (rspan <= IMG_CAP) {
            for (int k = t; k < rspan; k += 256) image[k] = a.n;   // sentinel
            __syncthreads();
            for (int j = e0 + t; j < e1; j += 256) {
                int en = a.ebuf[j];
                int s = en & 0x1FFFF;
                int dl = en >> 17;
                int pos = a.row_start[n0 + dl] - rbase + atomicAdd(&lcur[dl], 1);
                image[pos] = s;
            }
            __syncthreads();
            for (int k = t; k < rspan; k += 256) a.csr[rbase + k] = image[k];
        } else {                                    // statistically never
            __syncthreads();
            for (int j = e0 + t; j < e1; j += 256) {
                int en = a.ebuf[j];
                int s = en & 0x1FFFF;
                int dl = en >> 17;
                int pos = a.row_start[n0 + dl] + atomicAdd(&a.cursor[n0 + dl], 1);
                a.csr[pos] = s;
            }
            __syncthreads();
            for (int k = t; k < n1 - n0; k += 256) {
                int node = n0 + k;
                int c = a.cursor[node];
                for (int pos = a.row_start[node] + c; pos < a.row_start[node + 1]; pos++)
                    a.csr[pos] = a.n;
            }
        }
        __syncthreads();
    }
}

// ---------------- MFMA linear: hs[N,64] = dinv[r] * (in[N,K] @ w[K,64]) ----
template<int K, bool BF16IN>
__global__ __launch_bounds__(256) void lin_mfma(const void* __restrict__ in_,
                                                const float* __restrict__ w,
                                                const float* __restrict__ dinv,
                                                unsigned short* __restrict__ outbf, int n) {
    constexpr int XS = K + 8;
    __shared__ unsigned short xs[64 * XS];
    __shared__ unsigned short wt[64 * XS];
    int t = threadIdx.x;
    int row0 = blockIdx.x * 64;
    int nrows = n - row0; if (nrows > 64) nrows = 64;

    {
        const float4* w4 = (const float4*)w;
        for (int idx = t; idx < K * 16; idx += 256) {
            int k = idx >> 4, c4 = (idx & 15) * 4;
            float4 v = w4[idx];
            wt[(c4 + 0) * XS + k] = f2bf(v.x);
            wt[(c4 + 1) * XS + k] = f2bf(v.y);
            wt[(c4 + 2) * XS + k] = f2bf(v.z);
            wt[(c4 + 3) * XS + k] = f2bf(v.w);
        }
    }
    if constexpr (BF16IN) {
        const uint4* in4 = (const uint4*)((const unsigned short*)in_ + (size_t)row0 * K);
        int total8 = nrows * (K / 8);
        for (int idx = t; idx < total8; idx += 256) {
            int r = idx / (K / 8), kk = idx - r * (K / 8);
            uint4 v = in4[idx];
            *(uint4*)&xs[r * XS + kk * 8] = v;
        }
    } else {
        const float4* in4 = (const float4*)((const float*)in_ + (size_t)row0 * K);
        int total4 = nrows * (K / 4);
        for (int idx = t; idx < total4; idx += 256) {
            int r = idx / (K / 4), kk = idx - r * (K / 4);
            float4 v = in4[idx];
            ushort4 s4;
            s4.x = f2bf(v.x); s4.y = f2bf(v.y); s4.z = f2bf(v.z); s4.w = f2bf(v.w);
            *(ushort4*)&xs[r * XS + kk * 4] = s4;
        }
    }
    __syncthreads();

    int lane = t & 63;
    int wid = t >> 6;
    int quad = lane >> 4;
    int l15 = lane & 15;

    f32x4 acc[4];
#pragma unroll
    for (int cg_ = 0; cg_ < 4; cg_++) acc[cg_] = (f32x4){0.f, 0.f, 0.f, 0.f};

    const unsigned short* xrow = &xs[(wid * 16 + l15) * XS + quad * 8];
#pragma unroll
    for (int kc = 0; kc < K / 32; kc++) {
        bf16x8 bfrag = *(const bf16x8*)(xrow + kc * 32);
#pragma unroll
        for (int cg_ = 0; cg_ < 4; cg_++) {
            bf16x8 afrag = *(const bf16x8*)&wt[(cg_ * 16 + l15) * XS + kc * 32 + quad * 8];
            acc[cg_] = __builtin_amdgcn_mfma_f32_16x16x32_bf16(afrag, bfrag, acc[cg_], 0, 0, 0);
        }
    }

    int grow = row0 + wid * 16 + l15;
    if (grow < n) {
        float dv = dinv[grow];
#pragma unroll
        for (int cg_ = 0; cg_ < 4; cg_++) {
            ushort4 st;
            st.x = f2bf(acc[cg_][0] * dv);
            st.y = f2bf(acc[cg_][1] * dv);
            st.z = f2bf(acc[cg_][2] * dv);
            st.w = f2bf(acc[cg_][3] * dv);
            *(ushort4*)&outbf[(size_t)grow * 64 + cg_ * 16 + quad * 4] = st;
        }
    }
}

// ---------------- aggregation + bias + BN + ReLU (unroll 16) ----------------
// FUSE_POOL: instead of storing h, atomicAdd ReLU output into pooled[batch[i]].
template<bool FUSE_POOL>
__global__ __launch_bounds__(256) void agg_kernel(
        const unsigned short* __restrict__ hs, const int* __restrict__ row_start,
        const int* __restrict__ csr, const float* __restrict__ dinv,
        const float* __restrict__ bias, const float* __restrict__ gam,
        const float* __restrict__ bet, const float* __restrict__ mu,
        const float* __restrict__ var,
        unsigned short* __restrict__ out, const int* __restrict__ batch,
        float* __restrict__ pooled, int n) {
    int i = blockIdx.x * 4 + (threadIdx.x >> 6);
    int lane = threadIdx.x & 63;
    if (i >= n) return;
    float acc = bf2f(hs[(size_t)i * 64 + lane]);   // self-loop term (pre-scaled)
    int rs = row_start[i], re = row_start[i + 1];  // multiples of 8
    int j = rs;
    for (; j + 16 <= re; j += 16) {
        int4 c0 = *(const int4*)&csr[j];
        int4 c1 = *(const int4*)&csr[j + 4];
        int4 c2 = *(const int4*)&csr[j + 8];
        int4 c3 = *(const int4*)&csr[j + 12];
        float h0 = bf2f(hs[(size_t)c0.x * 64 + lane]);
        float h1 = bf2f(hs[(size_t)c0.y * 64 + lane]);
        float h2 = bf2f(hs[(size_t)c0.z * 64 + lane]);
        float h3 = bf2f(hs[(size_t)c0.w * 64 + lane]);
        float h4 = bf2f(hs[(size_t)c1.x * 64 + lane]);
        float h5 = bf2f(hs[(size_t)c1.y * 64 + lane]);
        float h6 = bf2f(hs[(size_t)c1.z * 64 + lane]);
        float h7 = bf2f(hs[(size_t)c1.w * 64 + lane]);
        float h8 = bf2f(hs[(size_t)c2.x * 64 + lane]);
        float h9 = bf2f(hs[(size_t)c2.y * 64 + lane]);
        float hA = bf2f(hs[(size_t)c2.z * 64 + lane]);
        float hB = bf2f(hs[(size_t)c2.w * 64 + lane]);
        float hC = bf2f(hs[(size_t)c3.x * 64 + lane]);
        float hD = bf2f(hs[(size_t)c3.y * 64 + lane]);
        float hE = bf2f(hs[(size_t)c3.z * 64 + lane]);
        float hF = bf2f(hs[(size_t)c3.w * 64 + lane]);
        acc += (((h0 + h1) + (h2 + h3)) + ((h4 + h5) + (h6 + h7)))
             + (((h8 + h9) + (hA + hB)) + ((hC + hD) + (hE + hF)));
    }
    for (; j < re; j += 8) {
        int4 c0 = *(const int4*)&csr[j];
        int4 c1 = *(const int4*)&csr[j + 4];
        float h0 = bf2f(hs[(size_t)c0.x * 64 + lane]);
        float h1 = bf2f(hs[(size_t)c0.y * 64 + lane]);
        float h2 = bf2f(hs[(size_t)c0.z * 64 + lane]);
        float h3 = bf2f(hs[(size_t)c0.w * 64 + lane]);
        float h4 = bf2f(hs[(size_t)c1.x * 64 + lane]);
        float h5 = bf2f(hs[(size_t)c1.y * 64 + lane]);
        float h6 = bf2f(hs[(size_t)c1.z * 64 + lane]);
        float h7 = bf2f(hs[(size_t)c1.w * 64 + lane]);
        acc += ((h0 + h1) + (h2 + h3)) + ((h4 + h5) + (h6 + h7));
    }
    float agg = acc * dinv[i];
    float scale = gam[lane] * rsqrtf(var[lane] + BN_EPS);
    float r = (agg + bias[lane] - mu[lane]) * scale + bet[lane];
    r = r > 0.f ? r : 0.f;
    if constexpr (FUSE_POOL) {
        int g = batch[i];                           // wave-uniform-ish broadcast
        atomicAdd(&pooled[(size_t)g * 64 + lane], r);
    } else {
        out[(size_t)i * 64 + lane] = f2bf(r);
    }
}

// ---------------- tiny MLP per graph ----------------
__global__ void mlp_kernel(const float* __restrict__ pooled,
                           const float* __restrict__ l1w, const float* __restrict__ l1b,
                           const float* __restrict__ l2w, const float* __restrict__ l2b,
                           float* __restrict__ out) {
    int g = blockIdx.x;
    int lane = threadIdx.x;
    __shared__ float p[64];
    __shared__ float h1[32];
    p[lane] = pooled[(size_t)g * 64 + lane];
    __syncthreads();
    if (lane < 32) {
        float a = l1b[lane];
#pragma unroll 8
        for (int k = 0; k < 64; k++) a += p[k] * l1w[k * 32 + lane];
        h1[lane] = a > 0.f ? a : 0.f;
    }
    __syncthreads();
    if (lane < 2) {
        float a = l2b[lane];
#pragma unroll 8
        for (int j = 0; j < 32; j++) a += h1[j] * l2w[j * 2 + lane];
        out[g * 2 + lane] = a;
    }
}

extern "C" void kernel_launch(void* const* d_in, const int* in_sizes, int n_in,
                              void* d_out, int out_size, void* d_ws, size_t ws_size,
                              hipStream_t stream) {
    const float* x     = (const float*)d_in[0];
    const int*   ei    = (const int*)d_in[1];
    const int*   batch = (const int*)d_in[2];
    const float* w0 = (const float*)d_in[3];
    const float* b0 = (const float*)d_in[4];
    const float* w1 = (const float*)d_in[5];
    const float* b1 = (const float*)d_in[6];
    const float* w2 = (const float*)d_in[7];
    const float* b2 = (const float*)d_in[8];
    const float* g0 = (const float*)d_in[9];
    const float* be0 = (const float*)d_in[10];
    const float* m0 = (const float*)d_in[11];
    const float* v0 = (const float*)d_in[12];
    const float* g1 = (const float*)d_in[13];
    const float* be1 = (const float*)d_in[14];
    const float* m1 = (const float*)d_in[15];
    const float* v1 = (const float*)d_in[16];
    const float* g2 = (const float*)d_in[17];
    const float* be2 = (const float*)d_in[18];
    const float* m2 = (const float*)d_in[19];
    const float* v2 = (const float*)d_in[20];
    const float* l1w = (const float*)d_in[21];
    const float* l1b = (const float*)d_in[22];
    const float* l2w = (const float*)d_in[23];
    const float* l2b = (const float*)d_in[24];
    float* out = (float*)d_out;

    const int N = in_sizes[2];
    const int E = in_sizes[1] / 2;
    const int G = out_size / 2;
    const int NBINS = (N + BIN_NODES - 1) / BIN_NODES;
    const int NB = (N + SCAN_CHUNK - 1) / SCAN_CHUNK;

    const int* src = ei;
    const int* dst = ei + E;

    // workspace layout
    char* p = (char*)d_ws;
    auto alloc = [&](size_t bytes) -> void* {
        void* r = (void*)p;
        p += (bytes + 255) & ~(size_t)255;
        return r;
    };
    const size_t CSR_CAP = ((size_t)E + 8 * (size_t)N + 3) & ~(size_t)3;
    float* dinvp    = (float*)alloc((size_t)N * 4);
    int*   cnt      = (int*)alloc((size_t)N * 4);
    int*   row_start= (int*)alloc((size_t)(N + 1) * 4);
    int*   cursor   = (int*)alloc((size_t)N * 4);
    int*   bsums    = (int*)alloc((size_t)NB * 4);
    int*   bincnt   = (int*)alloc((size_t)NBINS * 4);
    int*   bstart_e = (int*)alloc((size_t)(NBINS + 1) * 4);
    int*   bincur   = (int*)alloc((size_t)NBINS * 4);
    int*   ebuf     = (int*)alloc((size_t)E * 4);
    int*   csr      = (int*)alloc(CSR_CAP * 4);
    unsigned short* h_a = (unsigned short*)alloc((size_t)(N + 1) * 64 * 2); // +sentinel row
    unsigned short* h_b = (unsigned short*)alloc((size_t)N * 64 * 2);
    float* pooled   = (float*)alloc((size_t)G * 64 * 4);
    (void)ws_size;

    // ---- preprocessing: one cooperative kernel (zeroing fused in) ----
    PreArgs pa;
    pa.src = src; pa.dst = dst; pa.e = E;
    pa.bincnt = bincnt; pa.bstart_e = bstart_e; pa.bincur = bincur; pa.ebuf = ebuf;
    pa.cnt = cnt; pa.dinv = dinvp; pa.bsums = bsums; pa.row_start = row_start;
    pa.csr = csr; pa.cursor = cursor;
    pa.ha_sent = h_a + (size_t)N * 64; pa.pooled = pooled;
    pa.n = N; pa.nbins = NBINS; pa.nb = NB; pa.gpool = G;
    void* kargs[] = { (void*)&pa };
    hipLaunchCooperativeKernel((void*)preprocess_coop, dim3(COOP_GRID), dim3(256),
                               kargs, 0, stream);

    const int nblk = (N + 3) / 4;
    const int lblk = (N + 63) / 64;
    // ---- layer 0 ----
    lin_mfma<128, false><<<lblk, 256, 0, stream>>>(x, w0, dinvp, h_a, N);
    agg_kernel<false><<<nblk, 256, 0, stream>>>(h_a, row_start, csr, dinvp,
                                                b0, g0, be0, m0, v0, h_b,
                                                nullptr, nullptr, N);
    // ---- layer 1 ----
    lin_mfma<64, true><<<lblk, 256, 0, stream>>>(h_b, w1, dinvp, h_a, N);
    agg_kernel<false><<<nblk, 256, 0, stream>>>(h_a, row_start, csr, dinvp,
                                                b1, g1, be1, m1, v1, h_b,
                                                nullptr, nullptr, N);
    // ---- layer 2 (pool fused) ----
    lin_mfma<64, true><<<lblk, 256, 0, stream>>>(h_b, w2, dinvp, h_a, N);
    agg_kernel<true><<<nblk, 256, 0, stream>>>(h_a, row_start, csr, dinvp,
                                               b2, g2, be2, m2, v2, nullptr,
                                               batch, pooled, N);
    // ---- MLP ----
    mlp_kernel<<<G, 64, 0, stream>>>(pooled, l1w, l1b, l2w, l2b, out);
}

// Round 14
// 401.299 us; speedup vs baseline: 2.1670x; 2.1670x over previous
//
#include <hip/hip_runtime.h>
#include <hip/hip_bf16.h>

#define BN_EPS 1e-5f

typedef short bf16x8 __attribute__((ext_vector_type(8)));
typedef float f32x4 __attribute__((ext_vector_type(4)));

static __device__ __forceinline__ unsigned short f2bf(float f) {
    unsigned u = __float_as_uint(f);
    unsigned r = (u + 0x7FFF + ((u >> 16) & 1)) >> 16;
    return (unsigned short)r;
}
static __device__ __forceinline__ float bf2f(unsigned short s) {
    return __uint_as_float((unsigned)s << 16);
}
__device__ __forceinline__ int pad8i(int c) { return (c + 7) & ~7; }

#define BIN_SHIFT 9
#define BIN_NODES 512
#define P1_CHUNK 8192
#define IMG_CAP 12288
#define SCAN_CHUNK 1024

// ---------------- padded row scan (3-pass, chunk = 1024) ----------------
__global__ void scan_block_sums(const int* __restrict__ cnt, int* __restrict__ bsums, int n) {
    __shared__ int sdata[256];
    int b = blockIdx.x, t = threadIdx.x;
    int base = b * SCAN_CHUNK;
    int s = 0;
    for (int i = t; i < SCAN_CHUNK; i += 256) {
        int idx = base + i;
        if (idx < n) s += pad8i(cnt[idx]);
    }
    sdata[t] = s;
    __syncthreads();
    for (int off = 128; off > 0; off >>= 1) {
        if (t < off) sdata[t] += sdata[t + off];
        __syncthreads();
    }
    if (t == 0) bsums[b] = sdata[0];
}

// generic single-block exclusive scan (m <= 1024), in-place safe; out[m]=total
__global__ void scan_block_exclusive(const int* __restrict__ in, int* __restrict__ out, int m) {
    __shared__ int sd[256];
    int t = threadIdx.x;
    int base = t * 4;
    int v0 = (base + 0 < m) ? in[base + 0] : 0;
    int v1 = (base + 1 < m) ? in[base + 1] : 0;
    int v2 = (base + 2 < m) ? in[base + 2] : 0;
    int v3 = (base + 3 < m) ? in[base + 3] : 0;
    int tsum = v0 + v1 + v2 + v3;
    sd[t] = tsum;
    __syncthreads();
    for (int off = 1; off < 256; off <<= 1) {
        int x = (t >= off) ? sd[t - off] : 0;
        __syncthreads();
        sd[t] += x;
        __syncthreads();
    }
    int excl = sd[t] - tsum;
    if (base + 0 < m) out[base + 0] = excl;
    if (base + 1 < m) out[base + 1] = excl + v0;
    if (base + 2 < m) out[base + 2] = excl + v0 + v1;
    if (base + 3 < m) out[base + 3] = excl + v0 + v1 + v2;
    if (t == 255) out[m] = sd[255];
}

__global__ void scan_write(const int* __restrict__ cnt, const int* __restrict__ bsums,
                           int* __restrict__ row_start, int n) {
    __shared__ int sdata[256];
    int b = blockIdx.x, t = threadIdx.x;
    int base = b * SCAN_CHUNK + t * 4;
    int v0 = 0, v1 = 0, v2 = 0, v3 = 0;
    if (base + 0 < n) v0 = pad8i(cnt[base + 0]);
    if (base + 1 < n) v1 = pad8i(cnt[base + 1]);
    if (base + 2 < n) v2 = pad8i(cnt[base + 2]);
    if (base + 3 < n) v3 = pad8i(cnt[base + 3]);
    int tsum = v0 + v1 + v2 + v3;
    sdata[t] = tsum;
    __syncthreads();
    for (int off = 1; off < 256; off <<= 1) {       // inclusive Hillis-Steele
        int x = (t >= off) ? sdata[t - off] : 0;
        __syncthreads();
        sdata[t] += x;
        __syncthreads();
    }
    int excl = sdata[t] - tsum + bsums[b];
    if (base + 0 < n) row_start[base + 0] = excl;
    if (base + 1 < n) row_start[base + 1] = excl + v0;
    if (base + 2 < n) row_start[base + 2] = excl + v0 + v1;
    if (base + 3 < n) row_start[base + 3] = excl + v0 + v1 + v2;
    if (n - 1 >= base && n - 1 < base + 4)          // finalize total (padded end)
        row_start[n] = excl + v0 + v1 + v2 + v3;
}

// ---------------- bin-level histogram: LDS hist -> few global atomics -------
__global__ __launch_bounds__(256) void binhist_kernel(const int* __restrict__ dst,
                                                      int* __restrict__ bincnt,
                                                      int e, int nbins) {
    __shared__ int hist[256];
    int t = threadIdx.x;
    hist[t] = 0;
    __syncthreads();
    int c0 = blockIdx.x * P1_CHUNK;
    int iend = c0 + P1_CHUNK; if (iend > e) iend = e;
    for (int i = c0 + t; i < iend; i += 256)
        atomicAdd(&hist[dst[i] >> BIN_SHIFT], 1);
    __syncthreads();
    if (t < nbins && hist[t] > 0) atomicAdd(&bincnt[t], hist[t]);
}

// ---------------- phase 1: partition edges into 512-node bins --------------
__global__ __launch_bounds__(256) void phase1_kernel(
        const int* __restrict__ src, const int* __restrict__ dst,
        const int* __restrict__ bstart_e, int* __restrict__ bincur,
        int* __restrict__ ebuf, int e, int nbins) {
    __shared__ int hist[256], base[256], cur[256];
    int t = threadIdx.x;
    int c0 = blockIdx.x * P1_CHUNK;
    int iend = c0 + P1_CHUNK; if (iend > e) iend = e;
    hist[t] = 0;
    __syncthreads();
    for (int i = c0 + t; i < iend; i += 256)
        atomicAdd(&hist[dst[i] >> BIN_SHIFT], 1);
    __syncthreads();
    if (t < nbins && hist[t] > 0)
        base[t] = bstart_e[t] + atomicAdd(&bincur[t], hist[t]);
    cur[t] = 0;
    __syncthreads();
    for (int i = c0 + t; i < iend; i += 256) {
        int s = src[i], d = dst[i];
        int b = d >> BIN_SHIFT;
        int r = atomicAdd(&cur[b], 1);
        ebuf[base[b] + r] = s | ((d & (BIN_NODES - 1)) << 17);
    }
}

// ---------------- per-node counts + dinv (+ sentinel row zero) -------------
__global__ __launch_bounds__(256) void bincount_kernel(
        const int* __restrict__ ebuf, const int* __restrict__ bstart_e,
        int* __restrict__ cnt, float* __restrict__ dinv,
        unsigned short* __restrict__ ha_sent, int n) {
    __shared__ int c512[BIN_NODES];
    int b = blockIdx.x, t = threadIdx.x;
    if (b == 0 && t < 64) ha_sent[t] = 0;           // zero sentinel row (fused)
    for (int k = t; k < BIN_NODES; k += 256) c512[k] = 0;
    __syncthreads();
    int e0 = bstart_e[b], e1 = bstart_e[b + 1];
    for (int j = e0 + t; j < e1; j += 256)
        atomicAdd(&c512[ebuf[j] >> 17], 1);
    __syncthreads();
    int n0 = b * BIN_NODES;
    for (int k = t; k < BIN_NODES; k += 256) {
        int i = n0 + k;
        if (i < n) {
            int c = c512[k];
            cnt[i] = c;
            dinv[i] = rsqrtf((float)(c + 1));
        }
    }
}

// ---------------- phase 2: per-bin CSR build in LDS, coalesced write-out ----
__global__ __launch_bounds__(256) void phase2_kernel(
        const int* __restrict__ ebuf, const int* __restrict__ bstart_e,
        const int* __restrict__ row_start, int* __restrict__ csr,
        int* __restrict__ gcursor, int n, int sentinel) {
    __shared__ int image[IMG_CAP];
    __shared__ int lcur[BIN_NODES];
    int b = blockIdx.x, t = threadIdx.x;
    int n0 = b * BIN_NODES;
    int n1 = n0 + BIN_NODES; if (n1 > n) n1 = n;
    int rbase = row_start[n0];
    int rspan = row_start[n1] - rbase;
    int e0 = bstart_e[b], e1 = bstart_e[b + 1];
    for (int k = t; k < BIN_NODES; k += 256) lcur[k] = 0;
    if (rspan <= IMG_CAP) {
        for (int k = t; k < rspan; k += 256) image[k] = sentinel;
        __syncthreads();
        for (int j = e0 + t; j < e1; j += 256) {
            int en = ebuf[j];
            int s = en & 0x1FFFF;
            int dl = en >> 17;
            int pos = row_start[n0 + dl] - rbase + atomicAdd(&lcur[dl], 1);
            image[pos] = s;
        }
        __syncthreads();
        for (int k = t; k < rspan; k += 256) csr[rbase + k] = image[k];
    } else {                                        // statistically never
        for (int k = n0 + t; k < n1; k += 256) gcursor[k] = 0;
        __syncthreads();
        for (int j = e0 + t; j < e1; j += 256) {
            int en = ebuf[j];
            int s = en & 0x1FFFF;
            int dl = en >> 17;
            int pos = row_start[n0 + dl] + atomicAdd(&gcursor[n0 + dl], 1);
            csr[pos] = s;
        }
        __syncthreads();
        for (int k = t; k < n1 - n0; k += 256) {    // fill pads with sentinel
            int node = n0 + k;
            int c = gcursor[node];
            for (int pos = row_start[node] + c; pos < row_start[node + 1]; pos++)
                csr[pos] = sentinel;
        }
    }
}

// ---------------- MFMA linear: hs[N,64] = dinv[r] * (in[N,K] @ w[K,64]) ----
template<int K, bool BF16IN>
__global__ __launch_bounds__(256) void lin_mfma(const void* __restrict__ in_,
                                                const float* __restrict__ w,
                                                const float* __restrict__ dinv,
                                                unsigned short* __restrict__ outbf, int n) {
    constexpr int XS = K + 8;
    __shared__ unsigned short xs[64 * XS];
    __shared__ unsigned short wt[64 * XS];
    int t = threadIdx.x;
    int row0 = blockIdx.x * 64;
    int nrows = n - row0; if (nrows > 64) nrows = 64;

    {
        const float4* w4 = (const float4*)w;
        for (int idx = t; idx < K * 16; idx += 256) {
            int k = idx >> 4, c4 = (idx & 15) * 4;
            float4 v = w4[idx];
            wt[(c4 + 0) * XS + k] = f2bf(v.x);
            wt[(c4 + 1) * XS + k] = f2bf(v.y);
            wt[(c4 + 2) * XS + k] = f2bf(v.z);
            wt[(c4 + 3) * XS + k] = f2bf(v.w);
        }
    }
    if constexpr (BF16IN) {
        const uint4* in4 = (const uint4*)((const unsigned short*)in_ + (size_t)row0 * K);
        int total8 = nrows * (K / 8);
        for (int idx = t; idx < total8; idx += 256) {
            int r = idx / (K / 8), kk = idx - r * (K / 8);
            uint4 v = in4[idx];
            *(uint4*)&xs[r * XS + kk * 8] = v;
        }
    } else {
        const float4* in4 = (const float4*)((const float*)in_ + (size_t)row0 * K);
        int total4 = nrows * (K / 4);
        for (int idx = t; idx < total4; idx += 256) {
            int r = idx / (K / 4), kk = idx - r * (K / 4);
            float4 v = in4[idx];
            ushort4 s4;
            s4.x = f2bf(v.x); s4.y = f2bf(v.y); s4.z = f2bf(v.z); s4.w = f2bf(v.w);
            *(ushort4*)&xs[r * XS + kk * 4] = s4;
        }
    }
    __syncthreads();

    int lane = t & 63;
    int wid = t >> 6;
    int quad = lane >> 4;
    int l15 = lane & 15;

    f32x4 acc[4];
#pragma unroll
    for (int cg_ = 0; cg_ < 4; cg_++) acc[cg_] = (f32x4){0.f, 0.f, 0.f, 0.f};

    const unsigned short* xrow = &xs[(wid * 16 + l15) * XS + quad * 8];
#pragma unroll
    for (int kc = 0; kc < K / 32; kc++) {
        bf16x8 bfrag = *(const bf16x8*)(xrow + kc * 32);
#pragma unroll
        for (int cg_ = 0; cg_ < 4; cg_++) {
            bf16x8 afrag = *(const bf16x8*)&wt[(cg_ * 16 + l15) * XS + kc * 32 + quad * 8];
            acc[cg_] = __builtin_amdgcn_mfma_f32_16x16x32_bf16(afrag, bfrag, acc[cg_], 0, 0, 0);
        }
    }

    int grow = row0 + wid * 16 + l15;
    if (grow < n) {
        float dv = dinv[grow];
#pragma unroll
        for (int cg_ = 0; cg_ < 4; cg_++) {
            ushort4 st;
            st.x = f2bf(acc[cg_][0] * dv);
            st.y = f2bf(acc[cg_][1] * dv);
            st.z = f2bf(acc[cg_][2] * dv);
            st.w = f2bf(acc[cg_][3] * dv);
            *(ushort4*)&outbf[(size_t)grow * 64 + cg_ * 16 + quad * 4] = st;
        }
    }
}

// ---------------- aggregation + bias + BN + ReLU (unroll 16) ----------------
__global__ __launch_bounds__(256) void agg_kernel(
        const unsigned short* __restrict__ hs, const int* __restrict__ row_start,
        const int* __restrict__ csr, const float* __restrict__ dinv,
        const float* __restrict__ bias, const float* __restrict__ gam,
        const float* __restrict__ bet, const float* __restrict__ mu,
        const float* __restrict__ var,
        unsigned short* __restrict__ out, int n) {
    int i = blockIdx.x * 4 + (threadIdx.x >> 6);
    int lane = threadIdx.x & 63;
    if (i >= n) return;
    float acc = bf2f(hs[(size_t)i * 64 + lane]);   // self-loop term (pre-scaled)
    int rs = row_start[i], re = row_start[i + 1];  // multiples of 8
    int j = rs;
    for (; j + 16 <= re; j += 16) {
        int4 c0 = *(const int4*)&csr[j];
        int4 c1 = *(const int4*)&csr[j + 4];
        int4 c2 = *(const int4*)&csr[j + 8];
        int4 c3 = *(const int4*)&csr[j + 12];
        float h0 = bf2f(hs[(size_t)c0.x * 64 + lane]);
        float h1 = bf2f(hs[(size_t)c0.y * 64 + lane]);
        float h2 = bf2f(hs[(size_t)c0.z * 64 + lane]);
        float h3 = bf2f(hs[(size_t)c0.w * 64 + lane]);
        float h4 = bf2f(hs[(size_t)c1.x * 64 + lane]);
        float h5 = bf2f(hs[(size_t)c1.y * 64 + lane]);
        float h6 = bf2f(hs[(size_t)c1.z * 64 + lane]);
        float h7 = bf2f(hs[(size_t)c1.w * 64 + lane]);
        float h8 = bf2f(hs[(size_t)c2.x * 64 + lane]);
        float h9 = bf2f(hs[(size_t)c2.y * 64 + lane]);
        float hA = bf2f(hs[(size_t)c2.z * 64 + lane]);
        float hB = bf2f(hs[(size_t)c2.w * 64 + lane]);
        float hC = bf2f(hs[(size_t)c3.x * 64 + lane]);
        float hD = bf2f(hs[(size_t)c3.y * 64 + lane]);
        float hE = bf2f(hs[(size_t)c3.z * 64 + lane]);
        float hF = bf2f(hs[(size_t)c3.w * 64 + lane]);
        acc += (((h0 + h1) + (h2 + h3)) + ((h4 + h5) + (h6 + h7)))
             + (((h8 + h9) + (hA + hB)) + ((hC + hD) + (hE + hF)));
    }
    for (; j < re; j += 8) {
        int4 c0 = *(const int4*)&csr[j];
        int4 c1 = *(const int4*)&csr[j + 4];
        float h0 = bf2f(hs[(size_t)c0.x * 64 + lane]);
        float h1 = bf2f(hs[(size_t)c0.y * 64 + lane]);
        float h2 = bf2f(hs[(size_t)c0.z * 64 + lane]);
        float h3 = bf2f(hs[(size_t)c0.w * 64 + lane]);
        float h4 = bf2f(hs[(size_t)c1.x * 64 + lane]);
        float h5 = bf2f(hs[(size_t)c1.y * 64 + lane]);
        float h6 = bf2f(hs[(size_t)c1.z * 64 + lane]);
        float h7 = bf2f(hs[(size_t)c1.w * 64 + lane]);
        acc += ((h0 + h1) + (h2 + h3)) + ((h4 + h5) + (h6 + h7));
    }
    float agg = acc * dinv[i];
    float scale = gam[lane] * rsqrtf(var[lane] + BN_EPS);
    float r = (agg + bias[lane] - mu[lane]) * scale + bet[lane];
    out[(size_t)i * 64 + lane] = f2bf(r > 0.f ? r : 0.f);
}

// ---------------- pool stage 1: node-parallel segmented sum (bf16 in) ------
#define POOL_CHUNK 64
__global__ __launch_bounds__(256) void pool_kernel(const unsigned short* __restrict__ h,
                                                   const int* __restrict__ batch,
                                                   float* __restrict__ pooled, int n) {
    int wid = blockIdx.x * 4 + (threadIdx.x >> 6);
    int lane = threadIdx.x & 63;
    int start = wid * POOL_CHUNK;
    if (start >= n) return;
    int end = start + POOL_CHUNK; if (end > n) end = n;
    int cur = batch[start];
    float acc = 0.f;
    for (int i = start; i < end; i++) {
        int b = batch[i];
        if (b != cur) {
            atomicAdd(&pooled[(size_t)cur * 64 + lane], acc);
            acc = 0.f; cur = b;
        }
        acc += bf2f(h[(size_t)i * 64 + lane]);
    }
    atomicAdd(&pooled[(size_t)cur * 64 + lane], acc);
}

// ---------------- pool stage 2: tiny MLP per graph ----------------
__global__ void mlp_kernel(const float* __restrict__ pooled,
                           const float* __restrict__ l1w, const float* __restrict__ l1b,
                           const float* __restrict__ l2w, const float* __restrict__ l2b,
                           float* __restrict__ out) {
    int g = blockIdx.x;
    int lane = threadIdx.x;
    __shared__ float p[64];
    __shared__ float h1[32];
    p[lane] = pooled[(size_t)g * 64 + lane];
    __syncthreads();
    if (lane < 32) {
        float a = l1b[lane];
#pragma unroll 8
        for (int k = 0; k < 64; k++) a += p[k] * l1w[k * 32 + lane];
        h1[lane] = a > 0.f ? a : 0.f;
    }
    __syncthreads();
    if (lane < 2) {
        float a = l2b[lane];
#pragma unroll 8
        for (int j = 0; j < 32; j++) a += h1[j] * l2w[j * 2 + lane];
        out[g * 2 + lane] = a;
    }
}

extern "C" void kernel_launch(void* const* d_in, const int* in_sizes, int n_in,
                              void* d_out, int out_size, void* d_ws, size_t ws_size,
                              hipStream_t stream) {
    const float* x     = (const float*)d_in[0];
    const int*   ei    = (const int*)d_in[1];
    const int*   batch = (const int*)d_in[2];
    const float* w0 = (const float*)d_in[3];
    const float* b0 = (const float*)d_in[4];
    const float* w1 = (const float*)d_in[5];
    const float* b1 = (const float*)d_in[6];
    const float* w2 = (const float*)d_in[7];
    const float* b2 = (const float*)d_in[8];
    const float* g0 = (const float*)d_in[9];
    const float* be0 = (const float*)d_in[10];
    const float* m0 = (const float*)d_in[11];
    const float* v0 = (const float*)d_in[12];
    const float* g1 = (const float*)d_in[13];
    const float* be1 = (const float*)d_in[14];
    const float* m1 = (const float*)d_in[15];
    const float* v1 = (const float*)d_in[16];
    const float* g2 = (const float*)d_in[17];
    const float* be2 = (const float*)d_in[18];
    const float* m2 = (const float*)d_in[19];
    const float* v2 = (const float*)d_in[20];
    const float* l1w = (const float*)d_in[21];
    const float* l1b = (const float*)d_in[22];
    const float* l2w = (const float*)d_in[23];
    const float* l2b = (const float*)d_in[24];
    float* out = (float*)d_out;

    const int N = in_sizes[2];
    const int E = in_sizes[1] / 2;
    const int G = out_size / 2;
    const int NBINS = (N + BIN_NODES - 1) / BIN_NODES;
    const int NB = (N + SCAN_CHUNK - 1) / SCAN_CHUNK;

    const int* src = ei;
    const int* dst = ei + E;

    // workspace layout
    char* p = (char*)d_ws;
    auto alloc = [&](size_t bytes) -> void* {
        void* r = (void*)p;
        p += (bytes + 255) & ~(size_t)255;
        return r;
    };
    const size_t CSR_CAP = ((size_t)E + 8 * (size_t)N + 3) & ~(size_t)3;
    float* dinvp    = (float*)alloc((size_t)N * 4);
    int*   cnt      = (int*)alloc((size_t)N * 4);
    int*   row_start= (int*)alloc((size_t)(N + 1) * 4);
    int*   cursor   = (int*)alloc((size_t)N * 4);
    int*   bsums    = (int*)alloc((size_t)(NB + 1) * 4);
    int*   bincnt   = (int*)alloc((size_t)NBINS * 4);      // | contiguous zero
    int*   bstart_e = (int*)alloc((size_t)(NBINS + 1) * 4);//  | region
    int*   bincur   = (int*)alloc((size_t)NBINS * 4);      // |
    char*  bin_zero_end = p;
    int*   ebuf     = (int*)alloc((size_t)E * 4);
    int*   csr      = (int*)alloc(CSR_CAP * 4);
    unsigned short* h_a = (unsigned short*)alloc((size_t)(N + 1) * 64 * 2); // +sentinel row
    unsigned short* h_b = (unsigned short*)alloc((size_t)N * 64 * 2);
    float* pooled   = (float*)alloc((size_t)G * 64 * 4);
    (void)ws_size;

    // ---- graph preprocessing ----
    hipMemsetAsync(bincnt, 0, (size_t)(bin_zero_end - (char*)bincnt), stream);
    hipMemsetAsync(pooled, 0, (size_t)G * 64 * 4, stream);
    const int nchunks = (E + P1_CHUNK - 1) / P1_CHUNK;
    binhist_kernel<<<nchunks, 256, 0, stream>>>(dst, bincnt, E, NBINS);
    scan_block_exclusive<<<1, 256, 0, stream>>>(bincnt, bstart_e, NBINS);
    phase1_kernel<<<nchunks, 256, 0, stream>>>(src, dst, bstart_e, bincur, ebuf, E, NBINS);
    bincount_kernel<<<NBINS, 256, 0, stream>>>(ebuf, bstart_e, cnt, dinvp,
                                               h_a + (size_t)N * 64, N);
    scan_block_sums<<<NB, 256, 0, stream>>>(cnt, bsums, N);
    scan_block_exclusive<<<1, 256, 0, stream>>>(bsums, bsums, NB);
    scan_write<<<NB, 256, 0, stream>>>(cnt, bsums, row_start, N);
    phase2_kernel<<<NBINS, 256, 0, stream>>>(ebuf, bstart_e, row_start, csr,
                                             cursor, N, N);

    const int nblk = (N + 3) / 4;
    const int lblk = (N + 63) / 64;
    // ---- layer 0 ----
    lin_mfma<128, false><<<lblk, 256, 0, stream>>>(x, w0, dinvp, h_a, N);
    agg_kernel<<<nblk, 256, 0, stream>>>(h_a, row_start, csr, dinvp,
                                         b0, g0, be0, m0, v0, h_b, N);
    // ---- layer 1 ----
    lin_mfma<64, true><<<lblk, 256, 0, stream>>>(h_b, w1, dinvp, h_a, N);
    agg_kernel<<<nblk, 256, 0, stream>>>(h_a, row_start, csr, dinvp,
                                         b1, g1, be1, m1, v1, h_b, N);
    // ---- layer 2 ----
    lin_mfma<64, true><<<lblk, 256, 0, stream>>>(h_b, w2, dinvp, h_a, N);
    agg_kernel<<<nblk, 256, 0, stream>>>(h_a, row_start, csr, dinvp,
                                         b2, g2, be2, m2, v2, h_b, N);
    // ---- pool + MLP ----
    const int pwaves = (N + POOL_CHUNK - 1) / POOL_CHUNK;
    pool_kernel<<<(pwaves + 3) / 4, 256, 0, stream>>>(h_b, batch, pooled, N);
    mlp_kernel<<<G, 64, 0, stream>>>(pooled, l1w, l1b, l2w, l2b, out);
}

// Round 15
// 376.167 us; speedup vs baseline: 2.3118x; 1.0668x over previous
//
#include <hip/hip_runtime.h>
#include <hip/hip_bf16.h>

#define BN_EPS 1e-5f

typedef short bf16x8 __attribute__((ext_vector_type(8)));
typedef float f32x4 __attribute__((ext_vector_type(4)));

static __device__ __forceinline__ unsigned short f2bf(float f) {
    unsigned u = __float_as_uint(f);
    unsigned r = (u + 0x7FFF + ((u >> 16) & 1)) >> 16;
    return (unsigned short)r;
}
static __device__ __forceinline__ float bf2f(unsigned short s) {
    return __uint_as_float((unsigned)s << 16);
}
__device__ __forceinline__ int pad8i(int c) { return (c + 7) & ~7; }

#define BIN_SHIFT 9
#define BIN_NODES 512
#define P1_CHUNK 8192
#define IMG_CAP 12288
#define SCAN_CHUNK 1024

// ---------------- padded row scan (3-pass, chunk = 1024) ----------------
__global__ void scan_block_sums(const int* __restrict__ cnt, int* __restrict__ bsums, int n) {
    __shared__ int sdata[256];
    int b = blockIdx.x, t = threadIdx.x;
    int base = b * SCAN_CHUNK;
    int s = 0;
    for (int i = t; i < SCAN_CHUNK; i += 256) {
        int idx = base + i;
        if (idx < n) s += pad8i(cnt[idx]);
    }
    sdata[t] = s;
    __syncthreads();
    for (int off = 128; off > 0; off >>= 1) {
        if (t < off) sdata[t] += sdata[t + off];
        __syncthreads();
    }
    if (t == 0) bsums[b] = sdata[0];
}

// generic single-block exclusive scan (m <= 1024), in-place safe; out[m]=total
__global__ void scan_block_exclusive(const int* __restrict__ in, int* __restrict__ out, int m) {
    __shared__ int sd[256];
    int t = threadIdx.x;
    int base = t * 4;
    int v0 = (base + 0 < m) ? in[base + 0] : 0;
    int v1 = (base + 1 < m) ? in[base + 1] : 0;
    int v2 = (base + 2 < m) ? in[base + 2] : 0;
    int v3 = (base + 3 < m) ? in[base + 3] : 0;
    int tsum = v0 + v1 + v2 + v3;
    sd[t] = tsum;
    __syncthreads();
    for (int off = 1; off < 256; off <<= 1) {
        int x = (t >= off) ? sd[t - off] : 0;
        __syncthreads();
        sd[t] += x;
        __syncthreads();
    }
    int excl = sd[t] - tsum;
    if (base + 0 < m) out[base + 0] = excl;
    if (base + 1 < m) out[base + 1] = excl + v0;
    if (base + 2 < m) out[base + 2] = excl + v0 + v1;
    if (base + 3 < m) out[base + 3] = excl + v0 + v1 + v2;
    if (t == 255) out[m] = sd[255];
}

__global__ void scan_write(const int* __restrict__ cnt, const int* __restrict__ bsums,
                           int* __restrict__ row_start, int n) {
    __shared__ int sdata[256];
    int b = blockIdx.x, t = threadIdx.x;
    int base = b * SCAN_CHUNK + t * 4;
    int v0 = 0, v1 = 0, v2 = 0, v3 = 0;
    if (base + 0 < n) v0 = pad8i(cnt[base + 0]);
    if (base + 1 < n) v1 = pad8i(cnt[base + 1]);
    if (base + 2 < n) v2 = pad8i(cnt[base + 2]);
    if (base + 3 < n) v3 = pad8i(cnt[base + 3]);
    int tsum = v0 + v1 + v2 + v3;
    sdata[t] = tsum;
    __syncthreads();
    for (int off = 1; off < 256; off <<= 1) {       // inclusive Hillis-Steele
        int x = (t >= off) ? sdata[t - off] : 0;
        __syncthreads();
        sdata[t] += x;
        __syncthreads();
    }
    int excl = sdata[t] - tsum + bsums[b];
    if (base + 0 < n) row_start[base + 0] = excl;
    if (base + 1 < n) row_start[base + 1] = excl + v0;
    if (base + 2 < n) row_start[base + 2] = excl + v0 + v1;
    if (base + 3 < n) row_start[base + 3] = excl + v0 + v1 + v2;
    if (n - 1 >= base && n - 1 < base + 4)          // finalize total (padded end)
        row_start[n] = excl + v0 + v1 + v2 + v3;
}

// ---------------- bin-level histogram: LDS hist -> few global atomics -------
__global__ __launch_bounds__(256) void binhist_kernel(const int* __restrict__ dst,
                                                      int* __restrict__ bincnt,
                                                      int e, int nbins) {
    __shared__ int hist[256];
    int t = threadIdx.x;
    hist[t] = 0;
    __syncthreads();
    int c0 = blockIdx.x * P1_CHUNK;
    int iend = c0 + P1_CHUNK; if (iend > e) iend = e;
    for (int i = c0 + t; i < iend; i += 256)
        atomicAdd(&hist[dst[i] >> BIN_SHIFT], 1);
    __syncthreads();
    if (t < nbins && hist[t] > 0) atomicAdd(&bincnt[t], hist[t]);
}

// ---------------- phase 1: partition edges into 512-node bins --------------
__global__ __launch_bounds__(256) void phase1_kernel(
        const int* __restrict__ src, const int* __restrict__ dst,
        const int* __restrict__ bstart_e, int* __restrict__ bincur,
        int* __restrict__ ebuf, int e, int nbins) {
    __shared__ int hist[256], base[256], cur[256];
    int t = threadIdx.x;
    int c0 = blockIdx.x * P1_CHUNK;
    int iend = c0 + P1_CHUNK; if (iend > e) iend = e;
    hist[t] = 0;
    __syncthreads();
    for (int i = c0 + t; i < iend; i += 256)
        atomicAdd(&hist[dst[i] >> BIN_SHIFT], 1);
    __syncthreads();
    if (t < nbins && hist[t] > 0)
        base[t] = bstart_e[t] + atomicAdd(&bincur[t], hist[t]);
    cur[t] = 0;
    __syncthreads();
    for (int i = c0 + t; i < iend; i += 256) {
        int s = src[i], d = dst[i];
        int b = d >> BIN_SHIFT;
        int r = atomicAdd(&cur[b], 1);
        ebuf[base[b] + r] = s | ((d & (BIN_NODES - 1)) << 17);
    }
}

// ---------------- per-node counts + dinv (+ sentinel row zero) -------------
__global__ __launch_bounds__(256) void bincount_kernel(
        const int* __restrict__ ebuf, const int* __restrict__ bstart_e,
        int* __restrict__ cnt, float* __restrict__ dinv,
        unsigned short* __restrict__ ha_sent, int n) {
    __shared__ int c512[BIN_NODES];
    int b = blockIdx.x, t = threadIdx.x;
    if (b == 0 && t < 64) ha_sent[t] = 0;           // zero sentinel row (fused)
    for (int k = t; k < BIN_NODES; k += 256) c512[k] = 0;
    __syncthreads();
    int e0 = bstart_e[b], e1 = bstart_e[b + 1];
    for (int j = e0 + t; j < e1; j += 256)
        atomicAdd(&c512[ebuf[j] >> 17], 1);
    __syncthreads();
    int n0 = b * BIN_NODES;
    for (int k = t; k < BIN_NODES; k += 256) {
        int i = n0 + k;
        if (i < n) {
            int c = c512[k];
            cnt[i] = c;
            dinv[i] = rsqrtf((float)(c + 1));
        }
    }
}

// ---------------- phase 2: per-bin CSR build in LDS, coalesced write-out ----
__global__ __launch_bounds__(256) void phase2_kernel(
        const int* __restrict__ ebuf, const int* __restrict__ bstart_e,
        const int* __restrict__ row_start, int* __restrict__ csr,
        int* __restrict__ gcursor, int n, int sentinel) {
    __shared__ int image[IMG_CAP];
    __shared__ int lcur[BIN_NODES];
    int b = blockIdx.x, t = threadIdx.x;
    int n0 = b * BIN_NODES;
    int n1 = n0 + BIN_NODES; if (n1 > n) n1 = n;
    int rbase = row_start[n0];
    int rspan = row_start[n1] - rbase;
    int e0 = bstart_e[b], e1 = bstart_e[b + 1];
    for (int k = t; k < BIN_NODES; k += 256) lcur[k] = 0;
    if (rspan <= IMG_CAP) {
        for (int k = t; k < rspan; k += 256) image[k] = sentinel;
        __syncthreads();
        for (int j = e0 + t; j < e1; j += 256) {
            int en = ebuf[j];
            int s = en & 0x1FFFF;
            int dl = en >> 17;
            int pos = row_start[n0 + dl] - rbase + atomicAdd(&lcur[dl], 1);
            image[pos] = s;
        }
        __syncthreads();
        for (int k = t; k < rspan; k += 256) csr[rbase + k] = image[k];
    } else {                                        // statistically never
        for (int k = n0 + t; k < n1; k += 256) gcursor[k] = 0;
        __syncthreads();
        for (int j = e0 + t; j < e1; j += 256) {
            int en = ebuf[j];
            int s = en & 0x1FFFF;
            int dl = en >> 17;
            int pos = row_start[n0 + dl] + atomicAdd(&gcursor[n0 + dl], 1);
            csr[pos] = s;
        }
        __syncthreads();
        for (int k = t; k < n1 - n0; k += 256) {    // fill pads with sentinel
            int node = n0 + k;
            int c = gcursor[node];
            for (int pos = row_start[node] + c; pos < row_start[node + 1]; pos++)
                csr[pos] = sentinel;
        }
    }
}

// ---------------- MFMA linear: hs[N,64] = dinv[r] * (in[N,K] @ w[K,64]) ----
template<int K, bool BF16IN>
__global__ __launch_bounds__(256) void lin_mfma(const void* __restrict__ in_,
                                                const float* __restrict__ w,
                                                const float* __restrict__ dinv,
                                                unsigned short* __restrict__ outbf, int n) {
    constexpr int XS = K + 8;
    __shared__ unsigned short xs[64 * XS];
    __shared__ unsigned short wt[64 * XS];
    int t = threadIdx.x;
    int row0 = blockIdx.x * 64;
    int nrows = n - row0; if (nrows > 64) nrows = 64;

    {
        const float4* w4 = (const float4*)w;
        for (int idx = t; idx < K * 16; idx += 256) {
            int k = idx >> 4, c4 = (idx & 15) * 4;
            float4 v = w4[idx];
            wt[(c4 + 0) * XS + k] = f2bf(v.x);
            wt[(c4 + 1) * XS + k] = f2bf(v.y);
            wt[(c4 + 2) * XS + k] = f2bf(v.z);
            wt[(c4 + 3) * XS + k] = f2bf(v.w);
        }
    }
    if constexpr (BF16IN) {
        const uint4* in4 = (const uint4*)((const unsigned short*)in_ + (size_t)row0 * K);
        int total8 = nrows * (K / 8);
        for (int idx = t; idx < total8; idx += 256) {
            int r = idx / (K / 8), kk = idx - r * (K / 8);
            uint4 v = in4[idx];
            *(uint4*)&xs[r * XS + kk * 8] = v;
        }
    } else {
        const float4* in4 = (const float4*)((const float*)in_ + (size_t)row0 * K);
        int total4 = nrows * (K / 4);
        for (int idx = t; idx < total4; idx += 256) {
            int r = idx / (K / 4), kk = idx - r * (K / 4);
            float4 v = in4[idx];
            ushort4 s4;
            s4.x = f2bf(v.x); s4.y = f2bf(v.y); s4.z = f2bf(v.z); s4.w = f2bf(v.w);
            *(ushort4*)&xs[r * XS + kk * 4] = s4;
        }
    }
    __syncthreads();

    int lane = t & 63;
    int wid = t >> 6;
    int quad = lane >> 4;
    int l15 = lane & 15;

    f32x4 acc[4];
#pragma unroll
    for (int cg_ = 0; cg_ < 4; cg_++) acc[cg_] = (f32x4){0.f, 0.f, 0.f, 0.f};

    const unsigned short* xrow = &xs[(wid * 16 + l15) * XS + quad * 8];
#pragma unroll
    for (int kc = 0; kc < K / 32; kc++) {
        bf16x8 bfrag = *(const bf16x8*)(xrow + kc * 32);
#pragma unroll
        for (int cg_ = 0; cg_ < 4; cg_++) {
            bf16x8 afrag = *(const bf16x8*)&wt[(cg_ * 16 + l15) * XS + kc * 32 + quad * 8];
            acc[cg_] = __builtin_amdgcn_mfma_f32_16x16x32_bf16(afrag, bfrag, acc[cg_], 0, 0, 0);
        }
    }

    int grow = row0 + wid * 16 + l15;
    if (grow < n) {
        float dv = dinv[grow];
#pragma unroll
        for (int cg_ = 0; cg_ < 4; cg_++) {
            ushort4 st;
            st.x = f2bf(acc[cg_][0] * dv);
            st.y = f2bf(acc[cg_][1] * dv);
            st.z = f2bf(acc[cg_][2] * dv);
            st.w = f2bf(acc[cg_][3] * dv);
            *(ushort4*)&outbf[(size_t)grow * 64 + cg_ * 16 + quad * 4] = st;
        }
    }
}

// ---------------- aggregation + bias + BN + ReLU (uniform CSR walk) --------
// i/rs/re/csr-entries scalarized via readfirstlane -> CSR reads go through
// the SMEM pipe; gathers use 32-bit voffset (1 VALU each).
__global__ __launch_bounds__(256) void agg_kernel(
        const unsigned short* __restrict__ hs, const int* __restrict__ row_start,
        const int* __restrict__ csr, const float* __restrict__ dinv,
        const float* __restrict__ bias, const float* __restrict__ gam,
        const float* __restrict__ bet, const float* __restrict__ mu,
        const float* __restrict__ var,
        unsigned short* __restrict__ out, int n) {
    int iw = blockIdx.x * 4 + (threadIdx.x >> 6);
    unsigned lane = threadIdx.x & 63;
    if (iw >= n) return;                            // wave-uniform exit
    int i = __builtin_amdgcn_readfirstlane(iw);
    float acc = bf2f(hs[((unsigned)i << 6) + lane]); // self-loop (pre-scaled)
    int rs = __builtin_amdgcn_readfirstlane(row_start[i]);
    int re = __builtin_amdgcn_readfirstlane(row_start[i + 1]);  // x8 padded
    int j = rs;
    for (; j + 16 <= re; j += 16) {
        int s0 = __builtin_amdgcn_readfirstlane(csr[j + 0]);
        int s1 = __builtin_amdgcn_readfirstlane(csr[j + 1]);
        int s2 = __builtin_amdgcn_readfirstlane(csr[j + 2]);
        int s3 = __builtin_amdgcn_readfirstlane(csr[j + 3]);
        int s4 = __builtin_amdgcn_readfirstlane(csr[j + 4]);
        int s5 = __builtin_amdgcn_readfirstlane(csr[j + 5]);
        int s6 = __builtin_amdgcn_readfirstlane(csr[j + 6]);
        int s7 = __builtin_amdgcn_readfirstlane(csr[j + 7]);
        int s8 = __builtin_amdgcn_readfirstlane(csr[j + 8]);
        int s9 = __builtin_amdgcn_readfirstlane(csr[j + 9]);
        int sA = __builtin_amdgcn_readfirstlane(csr[j + 10]);
        int sB = __builtin_amdgcn_readfirstlane(csr[j + 11]);
        int sC = __builtin_amdgcn_readfirstlane(csr[j + 12]);
        int sD = __builtin_amdgcn_readfirstlane(csr[j + 13]);
        int sE = __builtin_amdgcn_readfirstlane(csr[j + 14]);
        int sF = __builtin_amdgcn_readfirstlane(csr[j + 15]);
        float h0 = bf2f(hs[((unsigned)s0 << 6) + lane]);
        float h1 = bf2f(hs[((unsigned)s1 << 6) + lane]);
        float h2 = bf2f(hs[((unsigned)s2 << 6) + lane]);
        float h3 = bf2f(hs[((unsigned)s3 << 6) + lane]);
        float h4 = bf2f(hs[((unsigned)s4 << 6) + lane]);
        float h5 = bf2f(hs[((unsigned)s5 << 6) + lane]);
        float h6 = bf2f(hs[((unsigned)s6 << 6) + lane]);
        float h7 = bf2f(hs[((unsigned)s7 << 6) + lane]);
        float h8 = bf2f(hs[((unsigned)s8 << 6) + lane]);
        float h9 = bf2f(hs[((unsigned)s9 << 6) + lane]);
        float hA = bf2f(hs[((unsigned)sA << 6) + lane]);
        float hB = bf2f(hs[((unsigned)sB << 6) + lane]);
        float hC = bf2f(hs[((unsigned)sC << 6) + lane]);
        float hD = bf2f(hs[((unsigned)sD << 6) + lane]);
        float hE = bf2f(hs[((unsigned)sE << 6) + lane]);
        float hF = bf2f(hs[((unsigned)sF << 6) + lane]);
        acc += (((h0 + h1) + (h2 + h3)) + ((h4 + h5) + (h6 + h7)))
             + (((h8 + h9) + (hA + hB)) + ((hC + hD) + (hE + hF)));
    }
    for (; j < re; j += 8) {
        int s0 = __builtin_amdgcn_readfirstlane(csr[j + 0]);
        int s1 = __builtin_amdgcn_readfirstlane(csr[j + 1]);
        int s2 = __builtin_amdgcn_readfirstlane(csr[j + 2]);
        int s3 = __builtin_amdgcn_readfirstlane(csr[j + 3]);
        int s4 = __builtin_amdgcn_readfirstlane(csr[j + 4]);
        int s5 = __builtin_amdgcn_readfirstlane(csr[j + 5]);
        int s6 = __builtin_amdgcn_readfirstlane(csr[j + 6]);
        int s7 = __builtin_amdgcn_readfirstlane(csr[j + 7]);
        float h0 = bf2f(hs[((unsigned)s0 << 6) + lane]);
        float h1 = bf2f(hs[((unsigned)s1 << 6) + lane]);
        float h2 = bf2f(hs[((unsigned)s2 << 6) + lane]);
        float h3 = bf2f(hs[((unsigned)s3 << 6) + lane]);
        float h4 = bf2f(hs[((unsigned)s4 << 6) + lane]);
        float h5 = bf2f(hs[((unsigned)s5 << 6) + lane]);
        float h6 = bf2f(hs[((unsigned)s6 << 6) + lane]);
        float h7 = bf2f(hs[((unsigned)s7 << 6) + lane]);
        acc += ((h0 + h1) + (h2 + h3)) + ((h4 + h5) + (h6 + h7));
    }
    float agg = acc * dinv[i];
    float scale = gam[lane] * rsqrtf(var[lane] + BN_EPS);
    float r = (agg + bias[lane] - mu[lane]) * scale + bet[lane];
    out[((unsigned)i << 6) + lane] = f2bf(r > 0.f ? r : 0.f);
}

// ---------------- pool stage 1: node-parallel segmented sum (bf16 in) ------
#define POOL_CHUNK 64
__global__ __launch_bounds__(256) void pool_kernel(const unsigned short* __restrict__ h,
                                                   const int* __restrict__ batch,
                                                   float* __restrict__ pooled, int n) {
    int wid = blockIdx.x * 4 + (threadIdx.x >> 6);
    int lane = threadIdx.x & 63;
    int start = wid * POOL_CHUNK;
    if (start >= n) return;
    int end = start + POOL_CHUNK; if (end > n) end = n;
    int cur = batch[start];
    float acc = 0.f;
    for (int i = start; i < end; i++) {
        int b = batch[i];
        if (b != cur) {
            atomicAdd(&pooled[(size_t)cur * 64 + lane], acc);
            acc = 0.f; cur = b;
        }
        acc += bf2f(h[(size_t)i * 64 + lane]);
    }
    atomicAdd(&pooled[(size_t)cur * 64 + lane], acc);
}

// ---------------- pool stage 2: tiny MLP per graph ----------------
__global__ void mlp_kernel(const float* __restrict__ pooled,
                           const float* __restrict__ l1w, const float* __restrict__ l1b,
                           const float* __restrict__ l2w, const float* __restrict__ l2b,
                           float* __restrict__ out) {
    int g = blockIdx.x;
    int lane = threadIdx.x;
    __shared__ float p[64];
    __shared__ float h1[32];
    p[lane] = pooled[(size_t)g * 64 + lane];
    __syncthreads();
    if (lane < 32) {
        float a = l1b[lane];
#pragma unroll 8
        for (int k = 0; k < 64; k++) a += p[k] * l1w[k * 32 + lane];
        h1[lane] = a > 0.f ? a : 0.f;
    }
    __syncthreads();
    if (lane < 2) {
        float a = l2b[lane];
#pragma unroll 8
        for (int j = 0; j < 32; j++) a += h1[j] * l2w[j * 2 + lane];
        out[g * 2 + lane] = a;
    }
}

extern "C" void kernel_launch(void* const* d_in, const int* in_sizes, int n_in,
                              void* d_out, int out_size, void* d_ws, size_t ws_size,
                              hipStream_t stream) {
    const float* x     = (const float*)d_in[0];
    const int*   ei    = (const int*)d_in[1];
    const int*   batch = (const int*)d_in[2];
    const float* w0 = (const float*)d_in[3];
    const float* b0 = (const float*)d_in[4];
    const float* w1 = (const float*)d_in[5];
    const float* b1 = (const float*)d_in[6];
    const float* w2 = (const float*)d_in[7];
    const float* b2 = (const float*)d_in[8];
    const float* g0 = (const float*)d_in[9];
    const float* be0 = (const float*)d_in[10];
    const float* m0 = (const float*)d_in[11];
    const float* v0 = (const float*)d_in[12];
    const float* g1 = (const float*)d_in[13];
    const float* be1 = (const float*)d_in[14];
    const float* m1 = (const float*)d_in[15];
    const float* v1 = (const float*)d_in[16];
    const float* g2 = (const float*)d_in[17];
    const float* be2 = (const float*)d_in[18];
    const float* m2 = (const float*)d_in[19];
    const float* v2 = (const float*)d_in[20];
    const float* l1w = (const float*)d_in[21];
    const float* l1b = (const float*)d_in[22];
    const float* l2w = (const float*)d_in[23];
    const float* l2b = (const float*)d_in[24];
    float* out = (float*)d_out;

    const int N = in_sizes[2];
    const int E = in_sizes[1] / 2;
    const int G = out_size / 2;
    const int NBINS = (N + BIN_NODES - 1) / BIN_NODES;
    const int NB = (N + SCAN_CHUNK - 1) / SCAN_CHUNK;

    const int* src = ei;
    const int* dst = ei + E;

    // workspace layout
    char* p = (char*)d_ws;
    auto alloc = [&](size_t bytes) -> void* {
        void* r = (void*)p;
        p += (bytes + 255) & ~(size_t)255;
        return r;
    };
    const size_t CSR_CAP = ((size_t)E + 8 * (size_t)N + 3) & ~(size_t)3;
    float* dinvp    = (float*)alloc((size_t)N * 4);
    int*   cnt      = (int*)alloc((size_t)N * 4);
    int*   row_start= (int*)alloc((size_t)(N + 1) * 4);
    int*   cursor   = (int*)alloc((size_t)N * 4);
    int*   bsums    = (int*)alloc((size_t)(NB + 1) * 4);
    int*   bincnt   = (int*)alloc((size_t)NBINS * 4);      // | contiguous zero
    int*   bstart_e = (int*)alloc((size_t)(NBINS + 1) * 4);//  | region
    int*   bincur   = (int*)alloc((size_t)NBINS * 4);      // |
    char*  bin_zero_end = p;
    int*   ebuf     = (int*)alloc((size_t)E * 4);
    int*   csr      = (int*)alloc(CSR_CAP * 4);
    unsigned short* h_a = (unsigned short*)alloc((size_t)(N + 1) * 64 * 2); // +sentinel row
    unsigned short* h_b = (unsigned short*)alloc((size_t)N * 64 * 2);
    float* pooled   = (float*)alloc((size_t)G * 64 * 4);
    (void)ws_size;

    // ---- graph preprocessing ----
    hipMemsetAsync(bincnt, 0, (size_t)(bin_zero_end - (char*)bincnt), stream);
    hipMemsetAsync(pooled, 0, (size_t)G * 64 * 4, stream);
    const int nchunks = (E + P1_CHUNK - 1) / P1_CHUNK;
    binhist_kernel<<<nchunks, 256, 0, stream>>>(dst, bincnt, E, NBINS);
    scan_block_exclusive<<<1, 256, 0, stream>>>(bincnt, bstart_e, NBINS);
    phase1_kernel<<<nchunks, 256, 0, stream>>>(src, dst, bstart_e, bincur, ebuf, E, NBINS);
    bincount_kernel<<<NBINS, 256, 0, stream>>>(ebuf, bstart_e, cnt, dinvp,
                                               h_a + (size_t)N * 64, N);
    scan_block_sums<<<NB, 256, 0, stream>>>(cnt, bsums, N);
    scan_block_exclusive<<<1, 256, 0, stream>>>(bsums, bsums, NB);
    scan_write<<<NB, 256, 0, stream>>>(cnt, bsums, row_start, N);
    phase2_kernel<<<NBINS, 256, 0, stream>>>(ebuf, bstart_e, row_start, csr,
                                             cursor, N, N);

    const int nblk = (N + 3) / 4;
    const int lblk = (N + 63) / 64;
    // ---- layer 0 ----
    lin_mfma<128, false><<<lblk, 256, 0, stream>>>(x, w0, dinvp, h_a, N);
    agg_kernel<<<nblk, 256, 0, stream>>>(h_a, row_start, csr, dinvp,
                                         b0, g0, be0, m0, v0, h_b, N);
    // ---- layer 1 ----
    lin_mfma<64, true><<<lblk, 256, 0, stream>>>(h_b, w1, dinvp, h_a, N);
    agg_kernel<<<nblk, 256, 0, stream>>>(h_a, row_start, csr, dinvp,
                                         b1, g1, be1, m1, v1, h_b, N);
    // ---- layer 2 ----
    lin_mfma<64, true><<<lblk, 256, 0, stream>>>(h_b, w2, dinvp, h_a, N);
    agg_kernel<<<nblk, 256, 0, stream>>>(h_a, row_start, csr, dinvp,
                                         b2, g2, be2, m2, v2, h_b, N);
    // ---- pool + MLP ----
    const int pwaves = (N + POOL_CHUNK - 1) / POOL_CHUNK;
    pool_kernel<<<(pwaves + 3) / 4, 256, 0, stream>>>(h_b, batch, pooled, N);
    mlp_kernel<<<G, 64, 0, stream>>>(pooled, l1w, l1b, l2w, l2b, out);
}